// Round 8
// baseline (681.675 us; speedup 1.0000x reference)
//
#include <hip/hip_runtime.h>

#define NN 50000
#define NNP 50048            // padded leading dim for aggT (mult of 16)
#define NE 400000
#define NBINS 512

// weight offsets
#define RL1ST 0              // l1s transposed: (192,64) col-contiguous
#define RL1VT 12288          // l1v transposed: (64,64)
#define RL2S  16384          // l2s original (160,32)
#define RL2V  21504          // l2v original (96,32)
#define WTOT  24576

#define SLUT_N ((NBINS+1)*256)

// ws layout (float offsets): aggT | wgt | slut | esh | ex | esnd | ints
#define AGGT_FL  ((size_t)256*NNP)
#define WGT_OFF  AGGT_FL
#define SLUT_OFF (WGT_OFF + WTOT)
#define ESH_OFF  (SLUT_OFF + SLUT_N)
#define EX_OFF   (ESH_OFF + (size_t)NE*4)
#define ESND_OFF (EX_OFF + NE)
#define INT_OFF  (ESND_OFF + NE)
#define TOT_FL   (INT_OFF + 3*NN + 1)
#define WS_NEED  (TOT_FL*4ull)        // 62,072,772 B < known ws floor 62.55 MB

#define S160 0.07905694150420949f
#define S96  0.10206207261596576f

__device__ __forceinline__ float sigf(float x){
  return __builtin_amdgcn_rcpf(1.0f + __expf(-x));
}
__device__ __forceinline__ float siluf(float x){ return x * sigf(x); }

// ---- weights: transpose l1s,l1v; copy l2s,l2v ----
__global__ __launch_bounds__(256) void convert_weights(
    const float* __restrict__ l1s, const float* __restrict__ l1v,
    const float* __restrict__ l2s, const float* __restrict__ l2v,
    float* __restrict__ wgt)
{
  int i = blockIdx.x*256 + threadIdx.x;
  if (i < 12288){ int o=i>>6, m=i&63; wgt[RL1ST + i] = l1s[m*192+o]; return; }
  if (i < 16384){ int t=i-12288; int o=t>>6, m=t&63; wgt[RL1VT + t] = l1v[m*64+o]; return; }
  if (i < 21504){ int t=i-16384; wgt[RL2S + t] = l2s[t]; return; }
  if (i < 24576){ int t=i-21504; wgt[RL2V + t] = l2v[t]; return; }
}

// ---- SLUT[bin][256]: scal(x) at bin edges, component-remapped ----
// c=m*8+q -> scal idx: q0->m, q1->32+m, q2..4->64+m, q5..7->96+m
__global__ __launch_bounds__(128) void build_lut(
    const float* __restrict__ w1, const float* __restrict__ b1,
    const float* __restrict__ w2, const float* __restrict__ b2,
    const float* __restrict__ w3, const float* __restrict__ b3,
    float* __restrict__ slut)
{
  __shared__ float h1[64], h2[64], scal[128];
  int bin = blockIdx.x;
  float x = (float)bin / (float)NBINS;
  int t = threadIdx.x;
  if (t < 64) h1[t] = siluf(fmaf(x, w1[t], b1[t]));
  __syncthreads();
  if (t < 64){
    float a = b2[t];
    for (int k=0;k<64;k++) a = fmaf(h1[k], w2[k*64+t], a);
    h2[t] = siluf(a);
  }
  __syncthreads();
  {
    float a = b3[t];
    for (int k=0;k<64;k++) a = fmaf(h2[k], w3[k*128+t], a);
    scal[t] = a;
  }
  __syncthreads();
  for (int c=t; c<256; c+=128){
    int m=c>>3, q=c&7;
    int idx = (q==0)? m : (q==1)? (32+m) : (q<5)? (64+m) : (96+m);
    slut[(size_t)bin*256 + c] = scal[idx];
  }
}

// ================= CSR build =================
__global__ __launch_bounds__(256) void count_kernel(
    const int* __restrict__ rcv, int* __restrict__ cnt)
{
  int e = blockIdx.x*256 + threadIdx.x;
  if (e < NE) atomicAdd(&cnt[rcv[e]], 1);
}

__global__ __launch_bounds__(1024) void scan_kernel(
    const int* __restrict__ cnt, int* __restrict__ offs, int* __restrict__ curs)
{
  __shared__ int sdata[1024];
  int tid = threadIdx.x;
  const int CH = 49;
  int base = tid*CH;
  int s = 0;
  for (int i=0;i<CH;i++){ int idx=base+i; if (idx<NN) s += cnt[idx]; }
  sdata[tid] = s;
  __syncthreads();
  for (int off=1; off<1024; off<<=1){
    int t = 0;
    if (tid >= off) t = sdata[tid-off];
    __syncthreads();
    sdata[tid] += t;
    __syncthreads();
  }
  int run = sdata[tid] - s;
  for (int i=0;i<CH;i++){
    int idx = base+i;
    if (idx < NN){ offs[idx]=run; curs[idx]=run; run += cnt[idx]; }
  }
  if (tid == 1023) offs[NN] = run;
}

// scatter + pre-gather edge payload into CSR order
__global__ __launch_bounds__(256) void scatter_kernel(
    const int* __restrict__ rcv, const int* __restrict__ snd,
    const float* __restrict__ nrm, const float* __restrict__ sh,
    int* __restrict__ curs,
    float4* __restrict__ esh, float* __restrict__ ex, int* __restrict__ esnd)
{
  int e = blockIdx.x*256 + threadIdx.x;
  if (e >= NE) return;
  int pos = atomicAdd(&curs[rcv[e]], 1);
  esh[pos]  = *(const float4*)(sh + 4*e);
  ex[pos]   = nrm[e];
  esnd[pos] = snd[e];
}

// ================= Edge+aggregate -> transposed agg ==========
__device__ __forceinline__ void edge_step(
    int p, const float4* __restrict__ esh, const float* __restrict__ ex,
    const int* __restrict__ esnd,
    const float* __restrict__ ns, const float* __restrict__ nv,
    const float4* __restrict__ slut4, int m, int odd, int lane,
    float& a0, float& a1, float& a2, float& a3)
{
  int s    = esnd[p];
  float x  = ex[p];
  float4 y = esh[p];
  float f = x * (float)NBINS;
  f = fminf(fmaxf(f, 0.0f), (float)NBINS - 0.001f);
  int bin = (int)f;
  float tt = f - (float)bin;
  float4 L0 = slut4[(size_t)bin*64 + lane];
  float4 L1 = slut4[(size_t)(bin+1)*64 + lane];
  float se = ns[(size_t)s*32 + m];
  const float* vp = nv + (size_t)s*96 + 3*m;
  float v0 = vp[0], v1 = vp[1], v2 = vp[2];
  float sc0 = fmaf(tt, L1.x-L0.x, L0.x);
  float sc1 = fmaf(tt, L1.y-L0.y, L0.y);
  float sc2 = fmaf(tt, L1.z-L0.z, L0.z);
  float sc3 = fmaf(tt, L1.w-L0.w, L0.w);
  const float inv_sqrt3 = 0.57735026918962576f;
  float A0,A1,A2,A3;
  if (!odd){
    float dot = fmaf(y.w, v2, fmaf(y.z, v1, y.y*v0));
    A0 = y.x*se; A1 = dot*inv_sqrt3; A2 = y.x*v0; A3 = y.x*v1;
  } else {
    A0 = y.x*v2; A1 = y.y*se; A2 = y.z*se; A3 = y.w*se;
  }
  a0 = fmaf(A0, sc0, a0);
  a1 = fmaf(A1, sc1, a1);
  a2 = fmaf(A2, sc2, a2);
  a3 = fmaf(A3, sc3, a3);
}

// wave per node (4 nodes/block), lane per 4 components; LDS transpose flush.
__global__ __launch_bounds__(256) void edge_agg_kernel(
    const float* __restrict__ ns, const float* __restrict__ nv,
    const float4* __restrict__ esh, const float* __restrict__ ex,
    const int* __restrict__ esnd,
    const int* __restrict__ offs, const float* __restrict__ slut,
    float* __restrict__ aggT)
{
  __shared__ float sacc[4][256];
  int wave = threadIdx.x >> 6;
  int lane = threadIdx.x & 63;
  int n = blockIdx.x*4 + wave;         // grid exact: n < NN
  int m = lane >> 1;
  int odd = lane & 1;
  int p0 = offs[n], p1 = offs[n+1];
  const float4* slut4 = (const float4*)slut;
  float a0=0.f, a1=0.f, a2=0.f, a3=0.f;
  float b0=0.f, b1=0.f, b2=0.f, b3=0.f;

  int p = p0;
  for (; p+1 < p1; p += 2){
    edge_step(p,   esh, ex, esnd, ns, nv, slut4, m, odd, lane, a0,a1,a2,a3);
    edge_step(p+1, esh, ex, esnd, ns, nv, slut4, m, odd, lane, b0,b1,b2,b3);
  }
  if (p < p1)
    edge_step(p, esh, ex, esnd, ns, nv, slut4, m, odd, lane, a0,a1,a2,a3);

  a0 += b0; a1 += b1; a2 += b2; a3 += b3;
  int deg = p1 - p0;
  float inv = (deg > 0) ? __builtin_amdgcn_rcpf((float)deg) : 1.0f;
  float4 o; o.x=a0*inv; o.y=a1*inv; o.z=a2*inv; o.w=a3*inv;
  *(float4*)(&sacc[wave][4*lane]) = o;
  __syncthreads();

  int t = threadIdx.x;
  float4 v;
  v.x = sacc[0][t]; v.y = sacc[1][t]; v.z = sacc[2][t]; v.w = sacc[3][t];
  *(float4*)(aggT + (size_t)t*NNP + blockIdx.x*4) = v;
}

// ================= Node scalar path: lane = node, no LDS ===================
__global__ __launch_bounds__(256,2) void node_s_kernel(
    const float* __restrict__ ns, const float* __restrict__ wgt,
    const float* __restrict__ aggT, float* __restrict__ out)
{
  int n = blockIdx.x*256 + threadIdx.x;
  if (n >= NN) return;
  float aggs[64];
  #pragma unroll
  for (int g=0;g<32;g++){
    aggs[g]    = aggT[(size_t)(8*g+0)*NNP + n];
    aggs[32+g] = aggT[(size_t)(8*g+1)*NNP + n];
  }
  float oacc[32];
  #pragma unroll
  for (int j=0;j<32;j++) oacc[j]=0.0f;
  const float* l1sT = wgt + RL1ST;
  const float* l2s  = wgt + RL2S;
  for (int o=0;o<128;o++){
    const float4* col = (const float4*)(l1sT + (size_t)o*64);
    float d0=0,d1=0,d2=0,d3=0;
    #pragma unroll
    for (int j=0;j<16;j++){
      float4 c4 = col[j];
      d0 = fmaf(aggs[4*j+0], c4.x, d0);
      d1 = fmaf(aggs[4*j+1], c4.y, d1);
      d2 = fmaf(aggs[4*j+2], c4.z, d2);
      d3 = fmaf(aggs[4*j+3], c4.w, d3);
    }
    float act = siluf(((d0+d1)+(d2+d3))*0.125f);
    const float4* row = (const float4*)(l2s + (size_t)o*32);
    #pragma unroll
    for (int j=0;j<8;j++){
      float4 w = row[j];
      oacc[4*j+0] = fmaf(act, w.x, oacc[4*j+0]);
      oacc[4*j+1] = fmaf(act, w.y, oacc[4*j+1]);
      oacc[4*j+2] = fmaf(act, w.z, oacc[4*j+2]);
      oacc[4*j+3] = fmaf(act, w.w, oacc[4*j+3]);
    }
  }
  const float4* sp = (const float4*)(ns + (size_t)n*32);
  #pragma unroll
  for (int q4=0;q4<8;q4++){
    float4 v = sp[q4];
    float vv[4] = {v.x, v.y, v.z, v.w};
    #pragma unroll
    for (int u=0;u<4;u++){
      float a = vv[u];
      const float4* row = (const float4*)(l2s + (size_t)(128+q4*4+u)*32);
      #pragma unroll
      for (int j=0;j<8;j++){
        float4 w = row[j];
        oacc[4*j+0] = fmaf(a, w.x, oacc[4*j+0]);
        oacc[4*j+1] = fmaf(a, w.y, oacc[4*j+1]);
        oacc[4*j+2] = fmaf(a, w.z, oacc[4*j+2]);
        oacc[4*j+3] = fmaf(a, w.w, oacc[4*j+3]);
      }
    }
  }
  float4* op = (float4*)(out + (size_t)n*128);
  #pragma unroll
  for (int j=0;j<8;j++){
    float4 o4;
    o4.x = oacc[4*j+0]*S160; o4.y = oacc[4*j+1]*S160;
    o4.z = oacc[4*j+2]*S160; o4.w = oacc[4*j+3]*S160;
    op[j] = o4;
  }
}

// ================= Node vector path: lane = node, k = blockIdx.y ===========
__global__ __launch_bounds__(256,2) void node_v_kernel(
    const float* __restrict__ nv, const float* __restrict__ wgt,
    const float* __restrict__ aggT, float* __restrict__ out)
{
  int n = blockIdx.x*256 + threadIdx.x;
  if (n >= NN) return;
  int k = blockIdx.y;
  float aggs[64], aggv[64];
  #pragma unroll
  for (int g=0;g<32;g++){
    aggs[g]    = aggT[(size_t)(8*g+0)*NNP + n];
    aggs[32+g] = aggT[(size_t)(8*g+1)*NNP + n];
    aggv[g]    = aggT[(size_t)(8*g+2+k)*NNP + n];
    aggv[32+g] = aggT[(size_t)(8*g+5+k)*NNP + n];
  }
  float oacc[32];
  #pragma unroll
  for (int j=0;j<32;j++) oacc[j]=0.0f;
  const float* l1sT = wgt + RL1ST;
  const float* l1vT = wgt + RL1VT;
  const float* l2v  = wgt + RL2V;
  for (int o=0;o<64;o++){
    const float4* colS = (const float4*)(l1sT + (size_t)(128+o)*64);
    const float4* colV = (const float4*)(l1vT + (size_t)o*64);
    float g0=0,g1=0,g2=0,g3=0;
    float d0=0,d1=0,d2=0,d3=0;
    #pragma unroll
    for (int j=0;j<16;j++){
      float4 cs = colS[j];
      float4 cv = colV[j];
      g0 = fmaf(aggs[4*j+0], cs.x, g0);
      g1 = fmaf(aggs[4*j+1], cs.y, g1);
      g2 = fmaf(aggs[4*j+2], cs.z, g2);
      g3 = fmaf(aggs[4*j+3], cs.w, g3);
      d0 = fmaf(aggv[4*j+0], cv.x, d0);
      d1 = fmaf(aggv[4*j+1], cv.y, d1);
      d2 = fmaf(aggv[4*j+2], cv.z, d2);
      d3 = fmaf(aggv[4*j+3], cv.w, d3);
    }
    float gate = sigf((((g0+g1)+(g2+g3)))*0.125f);
    float gv = ((((d0+d1)+(d2+d3)))*0.125f) * gate;
    const float4* row = (const float4*)(l2v + (size_t)o*32);
    #pragma unroll
    for (int j=0;j<8;j++){
      float4 w = row[j];
      oacc[4*j+0] = fmaf(gv, w.x, oacc[4*j+0]);
      oacc[4*j+1] = fmaf(gv, w.y, oacc[4*j+1]);
      oacc[4*j+2] = fmaf(gv, w.z, oacc[4*j+2]);
      oacc[4*j+3] = fmaf(gv, w.w, oacc[4*j+3]);
    }
  }
  const float* vp = nv + (size_t)n*96 + k;
  #pragma unroll 4
  for (int q=0;q<32;q++){
    float a = vp[3*q];
    const float4* row = (const float4*)(l2v + (size_t)(64+q)*32);
    #pragma unroll
    for (int j=0;j<8;j++){
      float4 w = row[j];
      oacc[4*j+0] = fmaf(a, w.x, oacc[4*j+0]);
      oacc[4*j+1] = fmaf(a, w.y, oacc[4*j+1]);
      oacc[4*j+2] = fmaf(a, w.z, oacc[4*j+2]);
      oacc[4*j+3] = fmaf(a, w.w, oacc[4*j+3]);
    }
  }
  float* op = out + (size_t)n*128 + 32 + k;
  #pragma unroll
  for (int j=0;j<32;j++) op[3*j] = oacc[j]*S96;
}

extern "C" void kernel_launch(void* const* d_in, const int* in_sizes, int n_in,
                              void* d_out, int out_size, void* d_ws, size_t ws_size,
                              hipStream_t stream) {
  const float* node_scalars = (const float*)d_in[0];
  const float* node_vectors = (const float*)d_in[1];
  const float* sh           = (const float*)d_in[2];
  const float* norm         = (const float*)d_in[3];
  const float* w1  = (const float*)d_in[4];
  const float* b1  = (const float*)d_in[5];
  const float* w2  = (const float*)d_in[6];
  const float* b2  = (const float*)d_in[7];
  const float* w3  = (const float*)d_in[8];
  const float* b3  = (const float*)d_in[9];
  const float* l1s = (const float*)d_in[10];
  const float* l1v = (const float*)d_in[11];
  const float* l2s = (const float*)d_in[12];
  const float* l2v = (const float*)d_in[13];
  const int* snd = (const int*)d_in[14];
  const int* rcv = (const int*)d_in[15];
  float* ws = (float*)d_ws;
  float* out = (float*)d_out;

  if (ws_size < WS_NEED) return;   // 62.07 MB; known ws floor 62.55 MB

  float* aggT = ws;
  float* wgt  = ws + WGT_OFF;
  float* slut = ws + SLUT_OFF;
  float4* esh = (float4*)(ws + ESH_OFF);
  float* ex   = ws + EX_OFF;
  int* esnd   = (int*)(ws + ESND_OFF);
  int* ib     = (int*)(ws + INT_OFF);
  int* cnt  = ib;
  int* offs = ib + NN;
  int* curs = ib + 2*NN + 1;

  hipMemsetAsync(cnt, 0, NN*sizeof(int), stream);

  convert_weights<<<(WTOT+255)/256, 256, 0, stream>>>(l1s, l1v, l2s, l2v, wgt);
  build_lut<<<NBINS+1, 128, 0, stream>>>(w1,b1,w2,b2,w3,b3, slut);

  count_kernel<<<(NE+255)/256, 256, 0, stream>>>(rcv, cnt);
  scan_kernel<<<1, 1024, 0, stream>>>(cnt, offs, curs);
  scatter_kernel<<<(NE+255)/256, 256, 0, stream>>>(
      rcv, snd, norm, sh, curs, esh, ex, esnd);

  edge_agg_kernel<<<NN/4, 256, 0, stream>>>(
      node_scalars, node_vectors, esh, ex, esnd, offs, slut, aggT);

  dim3 gs((NN+255)/256, 1);
  node_s_kernel<<<gs, 256, 0, stream>>>(node_scalars, wgt, aggT, out);
  dim3 gv((NN+255)/256, 3);
  node_v_kernel<<<gv, 256, 0, stream>>>(node_vectors, wgt, aggT, out);
}

// Round 9
// 574.451 us; speedup vs baseline: 1.1867x; 1.1867x over previous
//
#include <hip/hip_runtime.h>

#define NN 50000
#define NNP 50048            // padded leading dim for aggT
#define NE 400000
#define NBINS 512

// weight offsets
#define RL1ST 0              // l1s transposed: (192,64) col-contiguous
#define RL1VT 12288          // l1v transposed: (64,64)
#define RL2S  16384          // l2s original (160,32)
#define RL2V  21504          // l2v original (96,32)
#define WTOT  24576

#define SLUT_N ((NBINS+1)*256)

// ws layout (float offsets): aggT | wgt | slut | esh | ex | esnd | ints
#define AGGT_FL  ((size_t)256*NNP)
#define WGT_OFF  AGGT_FL
#define SLUT_OFF (WGT_OFF + WTOT)
#define ESH_OFF  (SLUT_OFF + SLUT_N)
#define EX_OFF   (ESH_OFF + (size_t)NE*4)
#define ESND_OFF (EX_OFF + NE)
#define INT_OFF  (ESND_OFF + NE)
#define TOT_FL   (INT_OFF + 3*NN + 1)
#define WS_NEED  (TOT_FL*4ull)        // ~62.07 MB < known ws floor 62.55 MB

#define S160 0.07905694150420949f
#define S96  0.10206207261596576f

__device__ __forceinline__ float sigf(float x){
  return __builtin_amdgcn_rcpf(1.0f + __expf(-x));
}
__device__ __forceinline__ float siluf(float x){ return x * sigf(x); }

// ---- weights: transpose l1s,l1v; copy l2s,l2v ----
__global__ __launch_bounds__(256) void convert_weights(
    const float* __restrict__ l1s, const float* __restrict__ l1v,
    const float* __restrict__ l2s, const float* __restrict__ l2v,
    float* __restrict__ wgt)
{
  int i = blockIdx.x*256 + threadIdx.x;
  if (i < 12288){ int o=i>>6, m=i&63; wgt[RL1ST + i] = l1s[m*192+o]; return; }
  if (i < 16384){ int t=i-12288; int o=t>>6, m=t&63; wgt[RL1VT + t] = l1v[m*64+o]; return; }
  if (i < 21504){ int t=i-16384; wgt[RL2S + t] = l2s[t]; return; }
  if (i < 24576){ int t=i-21504; wgt[RL2V + t] = l2v[t]; return; }
}

// ---- SLUT[bin][256]: scal(x) at bin edges, component-remapped ----
__global__ __launch_bounds__(128) void build_lut(
    const float* __restrict__ w1, const float* __restrict__ b1,
    const float* __restrict__ w2, const float* __restrict__ b2,
    const float* __restrict__ w3, const float* __restrict__ b3,
    float* __restrict__ slut)
{
  __shared__ float h1[64], h2[64], scal[128];
  int bin = blockIdx.x;
  float x = (float)bin / (float)NBINS;
  int t = threadIdx.x;
  if (t < 64) h1[t] = siluf(fmaf(x, w1[t], b1[t]));
  __syncthreads();
  if (t < 64){
    float a = b2[t];
    for (int k=0;k<64;k++) a = fmaf(h1[k], w2[k*64+t], a);
    h2[t] = siluf(a);
  }
  __syncthreads();
  {
    float a = b3[t];
    for (int k=0;k<64;k++) a = fmaf(h2[k], w3[k*128+t], a);
    scal[t] = a;
  }
  __syncthreads();
  for (int c=t; c<256; c+=128){
    int m=c>>3, q=c&7;
    int idx = (q==0)? m : (q==1)? (32+m) : (q<5)? (64+m) : (96+m);
    slut[(size_t)bin*256 + c] = scal[idx];
  }
}

// ================= CSR build =================
__global__ __launch_bounds__(256) void count_kernel(
    const int* __restrict__ rcv, int* __restrict__ cnt)
{
  int e = blockIdx.x*256 + threadIdx.x;
  if (e < NE) atomicAdd(&cnt[rcv[e]], 1);
}

__global__ __launch_bounds__(1024) void scan_kernel(
    const int* __restrict__ cnt, int* __restrict__ offs, int* __restrict__ curs)
{
  __shared__ int sdata[1024];
  int tid = threadIdx.x;
  const int CH = 49;
  int base = tid*CH;
  int s = 0;
  for (int i=0;i<CH;i++){ int idx=base+i; if (idx<NN) s += cnt[idx]; }
  sdata[tid] = s;
  __syncthreads();
  for (int off=1; off<1024; off<<=1){
    int t = 0;
    if (tid >= off) t = sdata[tid-off];
    __syncthreads();
    sdata[tid] += t;
    __syncthreads();
  }
  int run = sdata[tid] - s;
  for (int i=0;i<CH;i++){
    int idx = base+i;
    if (idx < NN){ offs[idx]=run; curs[idx]=run; run += cnt[idx]; }
  }
  if (tid == 1023) offs[NN] = run;
}

// scatter + pre-gather edge payload into CSR order
__global__ __launch_bounds__(256) void scatter_kernel(
    const int* __restrict__ rcv, const int* __restrict__ snd,
    const float* __restrict__ nrm, const float* __restrict__ sh,
    int* __restrict__ curs,
    float4* __restrict__ esh, float* __restrict__ ex, int* __restrict__ esnd)
{
  int e = blockIdx.x*256 + threadIdx.x;
  if (e >= NE) return;
  int pos = atomicAdd(&curs[rcv[e]], 1);
  esh[pos]  = *(const float4*)(sh + 4*e);
  ex[pos]   = nrm[e];
  esnd[pos] = snd[e];
}

// ================= Edge+aggregate -> transposed agg ==========
__device__ __forceinline__ void edge_step(
    int p, const float4* __restrict__ esh, const float* __restrict__ ex,
    const int* __restrict__ esnd,
    const float* __restrict__ ns, const float* __restrict__ nv,
    const float4* __restrict__ slut4, int m, int odd, int lane,
    float& a0, float& a1, float& a2, float& a3)
{
  int s    = esnd[p];
  float x  = ex[p];
  float4 y = esh[p];
  float f = x * (float)NBINS;
  f = fminf(fmaxf(f, 0.0f), (float)NBINS - 0.001f);
  int bin = (int)f;
  float tt = f - (float)bin;
  float4 L0 = slut4[(size_t)bin*64 + lane];
  float4 L1 = slut4[(size_t)(bin+1)*64 + lane];
  float se = ns[(size_t)s*32 + m];
  const float* vp = nv + (size_t)s*96 + 3*m;
  float v0 = vp[0], v1 = vp[1], v2 = vp[2];
  float sc0 = fmaf(tt, L1.x-L0.x, L0.x);
  float sc1 = fmaf(tt, L1.y-L0.y, L0.y);
  float sc2 = fmaf(tt, L1.z-L0.z, L0.z);
  float sc3 = fmaf(tt, L1.w-L0.w, L0.w);
  const float inv_sqrt3 = 0.57735026918962576f;
  float A0,A1,A2,A3;
  if (!odd){
    float dot = fmaf(y.w, v2, fmaf(y.z, v1, y.y*v0));
    A0 = y.x*se; A1 = dot*inv_sqrt3; A2 = y.x*v0; A3 = y.x*v1;
  } else {
    A0 = y.x*v2; A1 = y.y*se; A2 = y.z*se; A3 = y.w*se;
  }
  a0 = fmaf(A0, sc0, a0);
  a1 = fmaf(A1, sc1, a1);
  a2 = fmaf(A2, sc2, a2);
  a3 = fmaf(A3, sc3, a3);
}

// wave per node (4 nodes/block), lane per 4 components; LDS transpose flush.
__global__ __launch_bounds__(256) void edge_agg_kernel(
    const float* __restrict__ ns, const float* __restrict__ nv,
    const float4* __restrict__ esh, const float* __restrict__ ex,
    const int* __restrict__ esnd,
    const int* __restrict__ offs, const float* __restrict__ slut,
    float* __restrict__ aggT)
{
  __shared__ float sacc[4][256];
  int wave = threadIdx.x >> 6;
  int lane = threadIdx.x & 63;
  int n = blockIdx.x*4 + wave;         // grid exact: n < NN
  int m = lane >> 1;
  int odd = lane & 1;
  int p0 = offs[n], p1 = offs[n+1];
  const float4* slut4 = (const float4*)slut;
  float a0=0.f, a1=0.f, a2=0.f, a3=0.f;
  float b0=0.f, b1=0.f, b2=0.f, b3=0.f;

  int p = p0;
  for (; p+1 < p1; p += 2){
    edge_step(p,   esh, ex, esnd, ns, nv, slut4, m, odd, lane, a0,a1,a2,a3);
    edge_step(p+1, esh, ex, esnd, ns, nv, slut4, m, odd, lane, b0,b1,b2,b3);
  }
  if (p < p1)
    edge_step(p, esh, ex, esnd, ns, nv, slut4, m, odd, lane, a0,a1,a2,a3);

  a0 += b0; a1 += b1; a2 += b2; a3 += b3;
  int deg = p1 - p0;
  float inv = (deg > 0) ? __builtin_amdgcn_rcpf((float)deg) : 1.0f;
  float4 o; o.x=a0*inv; o.y=a1*inv; o.z=a2*inv; o.w=a3*inv;
  *(float4*)(&sacc[wave][4*lane]) = o;
  __syncthreads();

  int t = threadIdx.x;
  float4 v;
  v.x = sacc[0][t]; v.y = sacc[1][t]; v.z = sacc[2][t]; v.w = sacc[3][t];
  *(float4*)(aggT + (size_t)t*NNP + blockIdx.x*4) = v;
}

// ================= Node phase v4: 64 nodes/block, 4 roles, LDS out =========
// lane = node. Role 0: o_s (act cols + ns epilogue). Roles 1..3: o_v[k].
// Gates computed once (16 cols/role) -> sgate. Output staged in sout (pad 129)
// and flushed coalesced.
__global__ __launch_bounds__(256,3) void node_kernel(
    const float* __restrict__ ns, const float* __restrict__ nv,
    const float* __restrict__ wgt, const float* __restrict__ aggT,
    float* __restrict__ out)
{
  __shared__ float sgate[64*64];     // [o][node] 16 KB
  __shared__ float sout[64*129];     // 33 KB
  int tid = threadIdx.x;
  int lane = tid & 63, role = tid >> 6;
  int n0 = blockIdx.x*64;
  int nc = NN - n0; if (nc > 64) nc = 64;
  int n  = n0 + lane;
  int nsafe = (n < NN) ? n : (NN-1);
  const float* l1sT = wgt + RL1ST;

  // aggs: coalesced from aggT (pad cols < NNP safe for tail lanes)
  float aggs[64];
  #pragma unroll
  for (int g=0;g<32;g++){
    aggs[g]    = aggT[(size_t)(8*g+0)*NNP + n];
    aggs[32+g] = aggT[(size_t)(8*g+1)*NNP + n];
  }

  // Phase A: gates, 16 cols per role
  for (int t=0;t<16;t++){
    int o = role*16 + t;
    const float4* col = (const float4*)(l1sT + (size_t)(128+o)*64);
    float d0=0,d1=0,d2=0,d3=0;
    #pragma unroll
    for (int j=0;j<16;j++){
      float4 c4 = col[j];
      d0 = fmaf(aggs[4*j+0], c4.x, d0);
      d1 = fmaf(aggs[4*j+1], c4.y, d1);
      d2 = fmaf(aggs[4*j+2], c4.z, d2);
      d3 = fmaf(aggs[4*j+3], c4.w, d3);
    }
    sgate[o*64 + lane] = sigf(((d0+d1)+(d2+d3))*0.125f);
  }
  __syncthreads();

  if (role == 0){
    float oacc[32];
    #pragma unroll
    for (int j=0;j<32;j++) oacc[j]=0.0f;
    const float* l2s = wgt + RL2S;
    for (int o=0;o<128;o++){
      const float4* col = (const float4*)(l1sT + (size_t)o*64);
      float d0=0,d1=0,d2=0,d3=0;
      #pragma unroll
      for (int j=0;j<16;j++){
        float4 c4 = col[j];
        d0 = fmaf(aggs[4*j+0], c4.x, d0);
        d1 = fmaf(aggs[4*j+1], c4.y, d1);
        d2 = fmaf(aggs[4*j+2], c4.z, d2);
        d3 = fmaf(aggs[4*j+3], c4.w, d3);
      }
      float act = siluf(((d0+d1)+(d2+d3))*0.125f);
      const float4* row = (const float4*)(l2s + (size_t)o*32);
      #pragma unroll
      for (int j=0;j<8;j++){
        float4 w = row[j];
        oacc[4*j+0] = fmaf(act, w.x, oacc[4*j+0]);
        oacc[4*j+1] = fmaf(act, w.y, oacc[4*j+1]);
        oacc[4*j+2] = fmaf(act, w.z, oacc[4*j+2]);
        oacc[4*j+3] = fmaf(act, w.w, oacc[4*j+3]);
      }
    }
    const float4* sp = (const float4*)(ns + (size_t)nsafe*32);
    #pragma unroll
    for (int q4=0;q4<8;q4++){
      float4 v = sp[q4];
      float vv[4] = {v.x, v.y, v.z, v.w};
      #pragma unroll
      for (int u=0;u<4;u++){
        float a = vv[u];
        const float4* row = (const float4*)(wgt + RL2S + (size_t)(128+q4*4+u)*32);
        #pragma unroll
        for (int j=0;j<8;j++){
          float4 w = row[j];
          oacc[4*j+0] = fmaf(a, w.x, oacc[4*j+0]);
          oacc[4*j+1] = fmaf(a, w.y, oacc[4*j+1]);
          oacc[4*j+2] = fmaf(a, w.z, oacc[4*j+2]);
          oacc[4*j+3] = fmaf(a, w.w, oacc[4*j+3]);
        }
      }
    }
    #pragma unroll
    for (int j=0;j<32;j++) sout[lane*129 + j] = oacc[j]*S160;
  } else {
    int k = role - 1;
    float aggv[64];
    #pragma unroll
    for (int g=0;g<32;g++){
      aggv[g]    = aggT[(size_t)(8*g+2+k)*NNP + n];
      aggv[32+g] = aggT[(size_t)(8*g+5+k)*NNP + n];
    }
    float oacc[32];
    #pragma unroll
    for (int j=0;j<32;j++) oacc[j]=0.0f;
    const float* l1vT = wgt + RL1VT;
    const float* l2v  = wgt + RL2V;
    for (int o=0;o<64;o++){
      const float4* col = (const float4*)(l1vT + (size_t)o*64);
      float d0=0,d1=0,d2=0,d3=0;
      #pragma unroll
      for (int j=0;j<16;j++){
        float4 c4 = col[j];
        d0 = fmaf(aggv[4*j+0], c4.x, d0);
        d1 = fmaf(aggv[4*j+1], c4.y, d1);
        d2 = fmaf(aggv[4*j+2], c4.z, d2);
        d3 = fmaf(aggv[4*j+3], c4.w, d3);
      }
      float gv = (((d0+d1)+(d2+d3))*0.125f) * sgate[o*64 + lane];
      const float4* row = (const float4*)(l2v + (size_t)o*32);
      #pragma unroll
      for (int j=0;j<8;j++){
        float4 w = row[j];
        oacc[4*j+0] = fmaf(gv, w.x, oacc[4*j+0]);
        oacc[4*j+1] = fmaf(gv, w.y, oacc[4*j+1]);
        oacc[4*j+2] = fmaf(gv, w.z, oacc[4*j+2]);
        oacc[4*j+3] = fmaf(gv, w.w, oacc[4*j+3]);
      }
    }
    const float* vp = nv + (size_t)nsafe*96 + k;
    #pragma unroll 4
    for (int q=0;q<32;q++){
      float a = vp[3*q];
      const float4* row = (const float4*)(l2v + (size_t)(64+q)*32);
      #pragma unroll
      for (int j=0;j<8;j++){
        float4 w = row[j];
        oacc[4*j+0] = fmaf(a, w.x, oacc[4*j+0]);
        oacc[4*j+1] = fmaf(a, w.y, oacc[4*j+1]);
        oacc[4*j+2] = fmaf(a, w.z, oacc[4*j+2]);
        oacc[4*j+3] = fmaf(a, w.w, oacc[4*j+3]);
      }
    }
    #pragma unroll
    for (int j=0;j<32;j++) sout[lane*129 + 32 + k + 3*j] = oacc[j]*S96;
  }
  __syncthreads();

  // coalesced flush
  for (int i=tid; i<nc*128; i+=256){
    int nl = i>>7, c = i&127;
    out[(size_t)(n0+nl)*128 + c] = sout[nl*129 + c];
  }
}

extern "C" void kernel_launch(void* const* d_in, const int* in_sizes, int n_in,
                              void* d_out, int out_size, void* d_ws, size_t ws_size,
                              hipStream_t stream) {
  const float* node_scalars = (const float*)d_in[0];
  const float* node_vectors = (const float*)d_in[1];
  const float* sh           = (const float*)d_in[2];
  const float* norm         = (const float*)d_in[3];
  const float* w1  = (const float*)d_in[4];
  const float* b1  = (const float*)d_in[5];
  const float* w2  = (const float*)d_in[6];
  const float* b2  = (const float*)d_in[7];
  const float* w3  = (const float*)d_in[8];
  const float* b3  = (const float*)d_in[9];
  const float* l1s = (const float*)d_in[10];
  const float* l1v = (const float*)d_in[11];
  const float* l2s = (const float*)d_in[12];
  const float* l2v = (const float*)d_in[13];
  const int* snd = (const int*)d_in[14];
  const int* rcv = (const int*)d_in[15];
  float* ws = (float*)d_ws;
  float* out = (float*)d_out;

  if (ws_size < WS_NEED) return;

  float* aggT = ws;
  float* wgt  = ws + WGT_OFF;
  float* slut = ws + SLUT_OFF;
  float4* esh = (float4*)(ws + ESH_OFF);
  float* ex   = ws + EX_OFF;
  int* esnd   = (int*)(ws + ESND_OFF);
  int* ib     = (int*)(ws + INT_OFF);
  int* cnt  = ib;
  int* offs = ib + NN;
  int* curs = ib + 2*NN + 1;

  hipMemsetAsync(cnt, 0, NN*sizeof(int), stream);

  convert_weights<<<(WTOT+255)/256, 256, 0, stream>>>(l1s, l1v, l2s, l2v, wgt);
  build_lut<<<NBINS+1, 128, 0, stream>>>(w1,b1,w2,b2,w3,b3, slut);

  count_kernel<<<(NE+255)/256, 256, 0, stream>>>(rcv, cnt);
  scan_kernel<<<1, 1024, 0, stream>>>(cnt, offs, curs);
  scatter_kernel<<<(NE+255)/256, 256, 0, stream>>>(
      rcv, snd, norm, sh, curs, esh, ex, esnd);

  edge_agg_kernel<<<NN/4, 256, 0, stream>>>(
      node_scalars, node_vectors, esh, ex, esnd, offs, slut, aggT);

  node_kernel<<<(NN+63)/64, 256, 0, stream>>>(
      node_scalars, node_vectors, wgt, aggT, out);
}